// Round 16
// baseline (463.888 us; speedup 1.0000x reference)
//
#include <hip/hip_runtime.h>

// ---------------------------------------------------------------------------
// MultiHeadPooledSelfAttention on gfx950.
// R16 = R15 with the s_edge OOB fixed (R15 launched 256 blocks whose mapping
// produced head up to 63 >= 32 -> S overflow -> SIGABRT; correct XCD-grouped
// grid is 128 blocks: 8 xcd x 4 heads x 4 segs). R15 changes re-tested:
//  * mode-3 interior/edge split (-21% padded S compute)
//  * split-K x2 final projection
//  * emb folded into cvt launch
// Keeps: BK=64 staging XOR swizzle (0 conflicts), single-pass LDS epilogue,
// bias via acc-init, XCD grouping everywhere, wave-per-row softmax.
// ---------------------------------------------------------------------------

typedef unsigned short u16;
typedef __attribute__((ext_vector_type(8))) short short8;   // 8 x bf16
typedef __attribute__((ext_vector_type(4))) float floatx4;
typedef __attribute__((ext_vector_type(4))) unsigned short us4;

__device__ __forceinline__ u16 f2bf(float f) {
  union { float f; unsigned u; } x; x.f = f;
  unsigned r = (x.u + 0x7fffu + ((x.u >> 16) & 1u)) >> 16;
  return (u16)r;
}
__device__ __forceinline__ float bf2f(u16 u) {
  union { unsigned u; float f; } x; x.u = ((unsigned)u) << 16;
  return x.f;
}

__device__ __forceinline__ void gld_lds16(const void* g, void* l) {
  __builtin_amdgcn_global_load_lds(
      (const __attribute__((address_space(1))) void*)g,
      (__attribute__((address_space(3))) void*)l, 16, 0, 0);
}

// ---------------------------------------------------------------------------
// f32->bf16 conversions for x + 7 weights, PLUS pos-embed, one launch.
// ---------------------------------------------------------------------------
struct CvtArgs { const float* src[8]; u16* dst[8]; int n4[8]; };

__global__ __launch_bounds__(256) void cvt_all(CvtArgs a, int total4, float* __restrict__ e) {
  int t = blockIdx.x * 256 + threadIdx.x;
  if (t >= total4) {
    int et = (t - total4) * 4;                  // emb flat base, < 1024*512
    if (et >= 1024 * 512) return;
#pragma unroll
    for (int u = 0; u < 4; ++u) {
      int idx = et + u;
      int c = idx & 511, sp = idx >> 9;
      int y = sp >> 5, xg = sp & 31;
      int j = c & 127, seg = c >> 7;
      float omega = expf(-(float)j * (9.210340371976184f / 128.f));
      float arg = (float)((seg < 2) ? y : xg) * omega;
      e[idx] = (seg & 1) ? cosf(arg) : sinf(arg);
    }
    return;
  }
#pragma unroll
  for (int s = 0; s < 8; ++s) {
    if (t < a.n4[s]) {
      const float* sp = a.src[s] + (long)t * 4;
      u16* dp = a.dst[s] + (long)t * 4;
      float4 v = *(const float4*)sp;
      dp[0] = f2bf(v.x); dp[1] = f2bf(v.y); dp[2] = f2bf(v.z); dp[3] = f2bf(v.w);
      return;
    }
    t -= a.n4[s];
  }
}

// ---------------------------------------------------------------------------
__global__ __launch_bounds__(256) void cls_all(
    const u16* __restrict__ Q, const u16* __restrict__ K, const u16* __restrict__ V,
    u16* __restrict__ PQ, u16* __restrict__ PK, u16* __restrict__ PVt) {
  int t = blockIdx.x * 256 + threadIdx.x;    // < 32*512
  int bn = t >> 9, c = t & 511;
  long o = (long)bn * 1025 * 512 + c;
  PQ[o] = Q[o];
  PK[o] = K[o];
  PVt[((long)bn * 512 + c) * 1088] = V[o];
}

// ---------------------------------------------------------------------------
// S edge: per head, S[1024][kv] (kv<1025) and S[q][1024] (q<1024): 2049 dots
// of length 512 per head. Grid = nh*4 blocks.
//   nh==32: XCD-grouped: xcd=flat&7, s=flat>>3 (0..15), head=xcd+8*(s>>2),
//           seg=s&3  -> head 0..31.  [R15 bug: 256 blocks gave head up to 63]
//   else  : head=flat>>2, seg=flat&3 (fallback, correctness-first).
// ---------------------------------------------------------------------------
__global__ __launch_bounds__(256) void s_edge(const u16* __restrict__ PQ,
                                              const u16* __restrict__ PK,
                                              u16* __restrict__ S, int nh) {
  int flat = blockIdx.x;                 // nh*4
  int head, seg;
  if (nh == 32) {
    int xcd = flat & 7, s = flat >> 3;   // s: 0..15
    head = xcd + 8 * (s >> 2);           // 0..31
    seg = s & 3;
  } else {
    head = flat >> 2;
    seg = flat & 3;
  }
  const u16* pq = PQ + (long)head * 1025 * 512;
  const u16* pk = PK + (long)head * 1025 * 512;
  u16* sh = S + (long)head * 1025 * 1088;
#pragma unroll
  for (int i = 0; i < 3; ++i) {
    int local = i * 256 + (int)threadIdx.x;
    if (local >= 513) continue;
    int e = seg * 513 + local;
    if (e >= 2049) continue;
    int q, kv;
    if (e < 1025) { q = 1024; kv = e; }
    else { q = e - 1025; kv = 1024; }
    const u16* a = pq + (long)q * 512;
    const u16* b = pk + (long)kv * 512;
    float acc = 0.f;
    for (int k8 = 0; k8 < 64; ++k8) {
      short8 av = *(const short8*)(a + k8 * 8);
      short8 bv = *(const short8*)(b + k8 * 8);
#pragma unroll
      for (int u = 0; u < 8; ++u) acc += bf2f((u16)av[u]) * bf2f((u16)bv[u]);
    }
    sh[(long)q * 1088 + kv] = f2bf(acc * 0.04419417382415922f);
  }
}

// ---------------------------------------------------------------------------
// Softmax: one WAVE per row, 4 rows/block. XCD head-grouped.
// ---------------------------------------------------------------------------
__global__ __launch_bounds__(256) void softmax_rows(u16* __restrict__ S) {
  int flat = blockIdx.x;
  int xcd = flat & 7, s0 = flat >> 3;
  int zi = s0 / 257, blk = s0 - zi * 257;
  int head = xcd + 8 * zi;
  int wv = threadIdx.x >> 6, lane = threadIdx.x & 63;
  int row_i = blk * 4 + wv;
  if (row_i > 1024) return;
  u16* row = S + ((long)head * 1025 + row_i) * 1088;
  float v[16];
  float mx = -1e30f;
#pragma unroll
  for (int i = 0; i < 4; ++i) {
    us4 p = *(const us4*)(row + i * 256 + lane * 4);
#pragma unroll
    for (int e = 0; e < 4; ++e) { v[i * 4 + e] = bf2f(p[e]); mx = fmaxf(mx, v[i * 4 + e]); }
  }
  float e1024 = (lane == 0) ? bf2f(row[1024]) : -1e30f;
  mx = fmaxf(mx, e1024);
  for (int o = 32; o > 0; o >>= 1) mx = fmaxf(mx, __shfl_xor(mx, o, 64));
  float s = 0.f;
#pragma unroll
  for (int i = 0; i < 16; ++i) { v[i] = __expf(v[i] - mx); s += v[i]; }
  e1024 = (lane == 0) ? __expf(e1024 - mx) : 0.f;
  s += e1024;
  for (int o = 32; o > 0; o >>= 1) s += __shfl_xor(s, o, 64);
  float inv = 1.0f / s;
#pragma unroll
  for (int i = 0; i < 4; ++i) {
    us4 q;
#pragma unroll
    for (int e = 0; e < 4; ++e) q[e] = f2bf(v[i * 4 + e] * inv);
    *(us4*)(row + i * 256 + lane * 4) = q;
  }
  if (lane < 16) {
    us4 q;
#pragma unroll
    for (int e = 0; e < 4; ++e) q[e] = 0;
    if (lane == 0) q[0] = f2bf(e1024 * inv);
    *(us4*)(row + 1024 + lane * 4) = q;
  }
}

// ---------------------------------------------------------------------------
__global__ __launch_bounds__(256) void reduce2(const float* __restrict__ part,
                                               const float* __restrict__ bd,
                                               float* __restrict__ out) {
  int t = blockIdx.x * 256 + threadIdx.x;    // < 524800
  long i = (long)t * 4;
  const long STR = 4100ll * 512;
  float4 a = *(const float4*)(part + i);
  float4 b = *(const float4*)(part + i + STR);
  float4 bb = *(const float4*)(bd + (int)(i & 511));
  float4 r;
  r.x = a.x + b.x + bb.x;
  r.y = a.y + b.y + bb.y;
  r.z = a.z + b.z + bb.z;
  r.w = a.w + b.w + bb.w;
  *(float4*)(out + i) = r;
}

// ---------------------------------------------------------------------------
// GEMM-BT: C[m][n] = sum_k A[m][k]*B[n][k], bf16, 128x128 tile, BK=64,
// staging XOR swizzle. Mode 3 interior-only (8x8/head); mode 5 split-K x2.
// ---------------------------------------------------------------------------
struct GP {
  const u16* A; const u16* A2; const u16* B; const u16* B2;
  const float* c0; const float* c1; const float* c2;
  const float* emb; const u16* resid;
  u16* o0; u16* o1; u16* o2;
  float* of; int bz0;
};

template <int MODE>
__global__ __launch_bounds__(256) void gemm_bt(GP g) {
  constexpr int KLEN = (MODE == 5) ? 2048 : ((MODE == 4) ? 1088 : 512);
  constexpr int KITER = KLEN / 64;
  constexpr bool LDSEP = (MODE == 0 || MODE == 1 || MODE == 3 || MODE == 4);
  __shared__ u16 smem[16384];          // As | Bs staging; epilogue tile reuse
  u16* As = smem;
  u16* Bs = smem + 8192;
  const int tid = threadIdx.x;
  const int lane = tid & 63;
  const int wv = tid >> 6;
  const int wr = wv >> 1, wc = wv & 1;
  const int ccol = lane & 15;
  const int rgrp = lane >> 4;

  // Block -> (mt, nt, bz). XCD grouping (flat&7) for modes 1/2/3/4.
  int mt, nt, bz;
  if constexpr (MODE == 3 || MODE == 4) {
    constexpr int PER = (MODE == 3) ? 64 : 36;   // mode3: interior 8x8 only
    constexpr int NTW = (MODE == 3) ? 8 : 4;
    int flat = blockIdx.x;
    int xcd = flat & 7, s = flat >> 3;
    bz = xcd + 8 * (s / PER);
    int tile = s % PER;
    mt = tile / NTW;
    nt = tile % NTW;
  } else if constexpr (MODE == 1) {
    int flat = blockIdx.x;               // 2048 blocks
    int xcd = flat & 7, s = flat >> 3;   // s: 0..255
    bz = s >> 7;                         // 0 = Q-pool, 1 = K-pool
    int rem = s & 127;
    mt = xcd * 32 + (rem >> 2);          // contiguous 32-mt slice per XCD
    nt = rem & 3;
  } else if constexpr (MODE == 2) {
    int flat = blockIdx.x;               // 1024 blocks
    int xcd = flat & 7, s = flat >> 3;   // s: 0..127
    bz = 0;
    mt = xcd * 32 + (s >> 2);
    nt = s & 3;
  } else {
    mt = blockIdx.y; nt = blockIdx.x; bz = blockIdx.z;
  }
  const int gbz = g.bz0 + bz;

  const u16* Ap = g.A;
  const u16* Bp = g.B;
  if constexpr (MODE == 1) {
    if (bz == 1) { Ap = g.A2; Bp = g.B2; }
  }

  int a_row[4], b_row[4], kx[4];
#pragma unroll
  for (int c = 0; c < 4; ++c) {
    int idx = c * 256 + tid;
    int row = idx >> 3;                       // 0..127
    kx[c] = ((idx & 7) ^ (row & 7)) * 8;      // swizzled k-chunk offset (elems)
    {
      int r = mt * 128 + row;
      int off;
      if constexpr (MODE == 0) { r = r < 4099 ? r : 4099; off = r * 512; }
      else if constexpr (MODE == 1 || MODE == 2) { off = ((r >> 10) * 1025 + 1 + (r & 1023)) * 512; }
      else if constexpr (MODE == 3) { off = gbz * (1025 * 512) + r * 512; }
      else if constexpr (MODE == 4) { r = r < 1024 ? r : 1024; off = bz * (1025 * 1088) + r * 1088; }
      else { r = r < 4099 ? r : 4099; off = r * 4096; }
      a_row[c] = off;
    }
    {
      int r = nt * 128 + row;
      int off;
      if constexpr (MODE == 3) { off = gbz * (1025 * 512) + r * 512; }
      else if constexpr (MODE == 4) { off = gbz * (512 * 1088) + r * 1088; }
      else if constexpr (MODE == 5) { off = r * 4096; }
      else { off = r * 512; }
      b_row[c] = off;
    }
  }

  // Accumulators: modes 0/1/2 initialize with the per-column bias.
  floatx4 acc[4][4];
  {
    float binit[4] = {0.f, 0.f, 0.f, 0.f};
    if constexpr (MODE == 0) {
      int sec = nt >> 5;
      const float* bs = (sec == 0) ? g.c0 : (sec == 1) ? g.c1 : g.c2;
#pragma unroll
      for (int j = 0; j < 4; ++j) binit[j] = bs[(nt & 31) * 128 + wc * 64 + j * 16 + ccol];
    }
    if constexpr (MODE == 1) {
      const float* bs = bz ? g.c1 : g.c0;
#pragma unroll
      for (int j = 0; j < 4; ++j) binit[j] = bs[nt * 128 + wc * 64 + j * 16 + ccol];
    }
    if constexpr (MODE == 2) {
#pragma unroll
      for (int j = 0; j < 4; ++j) binit[j] = g.c0[nt * 128 + wc * 64 + j * 16 + ccol];
    }
#pragma unroll
    for (int i = 0; i < 4; ++i)
#pragma unroll
      for (int j = 0; j < 4; ++j)
#pragma unroll
        for (int rr = 0; rr < 4; ++rr) acc[i][j][rr] = binit[j];
  }

  const int kbase = (MODE == 5) ? bz * 2048 : 0;
  const int l15 = lane & 15;
  const int lq = lane >> 4;
  const int l7 = lane & 7;

  for (int kt = 0; kt < KITER; ++kt) {
    const int k0 = kbase + kt * 64;
#pragma unroll
    for (int c = 0; c < 4; ++c)
      gld_lds16(Ap + a_row[c] + k0 + kx[c], (char*)As + (c * 256 + wv * 64) * 16);
#pragma unroll
    for (int c = 0; c < 4; ++c)
      gld_lds16(Bp + b_row[c] + k0 + kx[c], (char*)Bs + (c * 256 + wv * 64) * 16);
    __syncthreads();
#pragma unroll
    for (int ks = 0; ks < 2; ++ks) {
      const int ch = ((ks * 4 + lq) ^ l7) * 8;
      short8 af[4], bf[4];
#pragma unroll
      for (int i = 0; i < 4; ++i)
        af[i] = *(const short8*)(As + (wr * 64 + i * 16 + l15) * 64 + ch);
#pragma unroll
      for (int j = 0; j < 4; ++j)
        bf[j] = *(const short8*)(Bs + (wc * 64 + j * 16 + l15) * 64 + ch);
#pragma unroll
      for (int i = 0; i < 4; ++i)
#pragma unroll
        for (int j = 0; j < 4; ++j)
          acc[i][j] = __builtin_amdgcn_mfma_f32_16x16x32_bf16(af[i], bf[j], acc[i][j], 0, 0, 0);
    }
    __syncthreads();
  }

  // ---- Epilogue ---- (C/D frag: col = lane&15, row = (lane>>4)*4 + reg)
  if constexpr (LDSEP) {
#pragma unroll
    for (int i = 0; i < 4; ++i)
#pragma unroll
      for (int j = 0; j < 4; ++j)
#pragma unroll
        for (int rr = 0; rr < 4; ++rr) {
          int lr = wr * 64 + i * 16 + rgrp * 4 + rr;
          int lc = wc * 64 + j * 16 + ccol;
          float v = acc[i][j][rr];
          if constexpr (MODE == 3) v *= 0.04419417382415922f;
          smem[lr * 128 + (lc ^ (rgrp << 4))] = f2bf(v);
        }
    __syncthreads();
#pragma unroll
    for (int q = 0; q < 8; ++q) {
      int cid = q * 256 + tid;
      int r = cid >> 4;                 // 0..127
      int c = cid & 15;                 // chunk
      int pc = c ^ ((((unsigned)r >> 2) & 3) << 1);
      short8 val = *(const short8*)(smem + r * 128 + pc * 8);
      int grow = mt * 128 + r;
      if constexpr (MODE == 0) {
        if (grow < 4100) {
          int sec = nt >> 5;                     // block-uniform
          int col = (nt & 31) * 128 + c * 8;     // 0..4095
          u16* ob = (sec == 0) ? g.o0 : (sec == 1) ? g.o1 : g.o2;
          int b = grow / 1025, l = grow - b * 1025;
          int n = col >> 9, ch2 = col & 511;
          *(short8*)(ob + ((long)(b * 8 + n) * 1025 + l) * 512 + ch2) = val;
        }
      } else if constexpr (MODE == 1) {
        int bn = grow >> 10, sp = grow & 1023;
        int gcol = nt * 128 + c * 8;             // 0..511
        short8 outv = val;
        if (bz == 0) {
          const float* ep = g.emb + sp * 512 + gcol;
          float4 e0 = *(const float4*)ep;
          float4 e1 = *(const float4*)(ep + 4);
          float ee[8] = {e0.x, e0.y, e0.z, e0.w, e1.x, e1.y, e1.z, e1.w};
#pragma unroll
          for (int e = 0; e < 8; ++e) outv[e] = (short)f2bf(bf2f((u16)val[e]) + ee[e]);
        }
        u16* dst = (bz == 0) ? g.o0 : g.o1;
        *(short8*)(dst + ((long)bn * 1025 + 1 + sp) * 512 + gcol) = outv;
      } else if constexpr (MODE == 3) {
        // interior only: grow < 1024, gcol < 1024 guaranteed
        *(short8*)(g.o0 + ((long)bz * 1025 + grow) * 1088 + nt * 128 + c * 8) = val;
      } else {  // MODE 4
        if (grow <= 1024) {
          int gcol0 = nt * 128 + c * 8;          // 0..511
          short8 outv = val;
          if (grow >= 1) {
            short8 rs = *(const short8*)(g.resid + ((long)gbz * 1025 + grow) * 512 + gcol0);
#pragma unroll
            for (int e = 0; e < 8; ++e)
              outv[e] = (short)f2bf(bf2f((u16)val[e]) + bf2f((u16)rs[e]));
          }
          int b = gbz >> 3, n = gbz & 7;
          *(short8*)(g.o0 + (((long)b * 1025 + grow) * 8 + n) * 512 + gcol0) = outv;
        }
      }
    }
  } else {
    // Scalar epilogue for modes 2 (transposed PVt pool; bias already in acc)
    // and 5 (f32 partials).
#pragma unroll
    for (int i = 0; i < 4; ++i) {
#pragma unroll
      for (int j = 0; j < 4; ++j) {
        const int gcol = nt * 128 + wc * 64 + j * 16 + ccol;
#pragma unroll
        for (int rr = 0; rr < 4; ++rr) {
          const int grow = mt * 128 + wr * 64 + i * 16 + rgrp * 4 + rr;
          float v = acc[i][j][rr];
          if constexpr (MODE == 2) {
            int bn = grow >> 10, sp = grow & 1023;
            g.o0[((long)bn * 512 + gcol) * 1088 + 1 + sp] = f2bf(v);
          } else {
            if (grow < 4100)
              g.of[((long)bz * 4100 + grow) * 512 + gcol] = v;   // partial
          }
        }
      }
    }
  }
}

// ---------------------------------------------------------------------------
extern "C" void kernel_launch(void* const* d_in, const int* in_sizes, int n_in,
                              void* d_out, int out_size, void* d_ws, size_t ws_size,
                              hipStream_t stream) {
  const float* x   = (const float*)d_in[0];
  const float* Wq  = (const float*)d_in[1];
  const float* bq  = (const float*)d_in[2];
  const float* Wk  = (const float*)d_in[3];
  const float* bk  = (const float*)d_in[4];
  const float* Wv  = (const float*)d_in[5];
  const float* bv  = (const float*)d_in[6];
  const float* Wpq = (const float*)d_in[7];
  const float* bpq = (const float*)d_in[8];
  const float* Wpk = (const float*)d_in[9];
  const float* bpk = (const float*)d_in[10];
  const float* Wpv = (const float*)d_in[11];
  const float* bpv = (const float*)d_in[12];
  const float* Wd  = (const float*)d_in[13];
  const float* bd  = (const float*)d_in[14];
  float* out = (float*)d_out;

  char* ws = (char*)d_ws;
  size_t off = 0;
  auto alloc = [&](size_t bytes) {
    char* p = ws + off;
    off += (bytes + 255) & ~(size_t)255;
    return p;
  };
  // Persistent through attention:
  u16* Wpqb = (u16*)alloc(512ull * 512 * 2);
  u16* Wpkb = (u16*)alloc(512ull * 512 * 2);
  u16* Wpvb = (u16*)alloc(512ull * 512 * 2);
  u16* Wdb  = (u16*)alloc(4096ull * 512 * 2);
  u16* Q    = (u16*)alloc(32ull * 1025 * 512 * 2);
  u16* PQ   = (u16*)alloc(32ull * 1025 * 512 * 2);   // later: f32 partials
  u16* PK   = (u16*)alloc(32ull * 1025 * 512 * 2);   // later: stk (nchunk=1)
  u16* PVt  = (u16*)alloc(32ull * 512 * 1088 * 2);
  // Dead-by-attention group (S aliases from here):
  size_t s_off = off;
  u16* K    = (u16*)alloc(32ull * 1025 * 512 * 2);
  u16* V    = (u16*)alloc(32ull * 1025 * 512 * 2);
  u16* xb   = (u16*)alloc(4100ull * 512 * 2);
  u16* Wqb  = (u16*)alloc(4096ull * 512 * 2);   // Wqb|Wkb|Wvb contiguous
  u16* Wkb  = (u16*)alloc(4096ull * 512 * 2);
  u16* Wvb  = (u16*)alloc(4096ull * 512 * 2);
  float* embp = (float*)alloc(1024ull * 512 * 4);
  size_t fixed_need = off;
  u16* S = (u16*)(ws + s_off);
  float* part = (float*)PQ;   // PQ dead before partials written
  (void)in_sizes; (void)n_in; (void)out_size;

  const size_t sbytes = 1025ull * 1088 * 2;
  size_t need1 = s_off + 32ull * sbytes;
  size_t need2 = s_off + 16ull * sbytes;
  size_t stk4_off = s_off + ((8ull * sbytes + 255) & ~(size_t)255);
  size_t need4 = stk4_off + 4100ull * 4096 * 2;
  int nchunk;
  u16* stk;
  if (ws_size >= need1)      { nchunk = 1; stk = PK; }   // PK dead after mode 3
  else if (ws_size >= need2 && ws_size >= fixed_need) { nchunk = 2; stk = PK; }
  else if (ws_size >= need4 && ws_size >= fixed_need) {
    nchunk = 4; stk = (u16*)(ws + stk4_off);
  } else return;  // clean fail instead of GPU fault
  if (nchunk == 2) {
    size_t stk2_off = s_off + ((16ull * sbytes + 255) & ~(size_t)255);
    if (ws_size >= stk2_off + 4100ull * 4096 * 2) stk = (u16*)(ws + stk2_off);
    else {
      nchunk = 4;
      if (ws_size >= need4) stk = (u16*)(ws + stk4_off);
      else return;
    }
  }
  int hpc = 32 / nchunk;

  // 1) dtype conversions + pos-embed (one launch)
  CvtArgs ca;
  ca.src[0] = x;   ca.dst[0] = xb;   ca.n4[0] = 4100 * 512 / 4;
  ca.src[1] = Wq;  ca.dst[1] = Wqb;  ca.n4[1] = 4096 * 512 / 4;
  ca.src[2] = Wk;  ca.dst[2] = Wkb;  ca.n4[2] = 4096 * 512 / 4;
  ca.src[3] = Wv;  ca.dst[3] = Wvb;  ca.n4[3] = 4096 * 512 / 4;
  ca.src[4] = Wpq; ca.dst[4] = Wpqb; ca.n4[4] = 512 * 512 / 4;
  ca.src[5] = Wpk; ca.dst[5] = Wpkb; ca.n4[5] = 512 * 512 / 4;
  ca.src[6] = Wpv; ca.dst[6] = Wpvb; ca.n4[6] = 512 * 512 / 4;
  ca.src[7] = Wd;  ca.dst[7] = Wdb;  ca.n4[7] = 512 * 4096 / 4;
  int total4 = 0;
  for (int s = 0; s < 8; ++s) total4 += ca.n4[s];
  int grid1 = (total4 + 1024 * 512 / 4 + 255) / 256;
  cvt_all<<<grid1, 256, 0, stream>>>(ca, total4, embp);

  // 2) merged Q+K+V projection (B = [Wq|Wk|Wv], N=12288), one dispatch
  {
    GP g = {};
    g.A = xb; g.B = Wqb;
    g.c0 = bq; g.c1 = bk; g.c2 = bv;
    g.o0 = Q; g.o1 = K; g.o2 = V;
    gemm_bt<0><<<dim3(96, 33, 1), 256, 0, stream>>>(g);
  }

  // 3) cls passthrough (one kernel)
  cls_all<<<(32 * 512) / 256, 256, 0, stream>>>(Q, K, V, PQ, PK, PVt);

  // 4) pools: Q(+emb) and K in one lean mode-1 dispatch; V pool separate
  {
    GP g = {};
    g.A = Q; g.A2 = K; g.B = Wpqb; g.B2 = Wpkb;
    g.c0 = bpq; g.c1 = bpk; g.emb = embp;
    g.o0 = PQ; g.o1 = PK;
    gemm_bt<1><<<dim3(2048, 1, 1), 256, 0, stream>>>(g);
  }
  {
    GP g = {};
    g.A = V; g.B = Wpvb; g.c0 = bpv; g.o0 = PVt;
    gemm_bt<2><<<dim3(1024, 1, 1), 256, 0, stream>>>(g);
  }
  // K, V, xb, Wqkv, embp now dead -> S aliases them.

  // 5) attention: interior S tiles + S edge -> softmax -> O (+Q resid).
  for (int c = 0; c < nchunk; ++c) {
    GP g3 = {}; g3.A = PQ; g3.B = PK; g3.o0 = S; g3.bz0 = c * hpc;
    gemm_bt<3><<<dim3(64 * hpc, 1, 1), 256, 0, stream>>>(g3);
    s_edge<<<hpc * 4, 256, 0, stream>>>(
        PQ + (long)c * hpc * 1025 * 512, PK + (long)c * hpc * 1025 * 512, S, hpc);
    softmax_rows<<<257 * hpc, 256, 0, stream>>>(S);
    GP g4 = {}; g4.A = S; g4.B = PVt; g4.resid = Q; g4.o0 = stk; g4.bz0 = c * hpc;
    gemm_bt<4><<<dim3(36 * hpc, 1, 1), 256, 0, stream>>>(g4);
  }
  // PQ dead -> f32 partials alias it.

  // 6) final projection, split-K x2 -> partials, then reduce (+bias)
  {
    GP g = {}; g.A = stk; g.B = Wdb; g.of = part;
    gemm_bt<5><<<dim3(4, 33, 2), 256, 0, stream>>>(g);
  }
  reduce2<<<(4100 * 512 / 4 + 255) / 256, 256, 0, stream>>>(part, bd, out);
}

// Round 17
// 446.681 us; speedup vs baseline: 1.0385x; 1.0385x over previous
//
#include <hip/hip_runtime.h>

// ---------------------------------------------------------------------------
// MultiHeadPooledSelfAttention on gfx950.
// R17 = R16 +
//  * token-order permutation: cls token moved to index 1024 in PQ/PK/S/PVt
//    (spatial at 0..1023). Makes mode-2's PVt spatial writes 16B-aligned ->
//    LDS-transposed vector epilogue (8 dwordx4 stores vs 64 scalar).
//    Mode-4 epilogue maps back: l = (q==1024) ? 0 : q+1.
//  * cls passthrough folded into mode-0 epilogue (cls_all launch removed).
//  * s_edge at one-dot-per-thread (hpc*8 blocks; R16's 2 dots/thread at 128
//    blocks was eating the mode-3 interior-split gain).
// Keeps: BK=64 staging XOR swizzle (0 conflicts), single-pass LDS epilogue,
// bias via acc-init, XCD grouping everywhere, wave softmax, split-K x2 final.
// ---------------------------------------------------------------------------

typedef unsigned short u16;
typedef __attribute__((ext_vector_type(8))) short short8;   // 8 x bf16
typedef __attribute__((ext_vector_type(4))) float floatx4;
typedef __attribute__((ext_vector_type(4))) unsigned short us4;

__device__ __forceinline__ u16 f2bf(float f) {
  union { float f; unsigned u; } x; x.f = f;
  unsigned r = (x.u + 0x7fffu + ((x.u >> 16) & 1u)) >> 16;
  return (u16)r;
}
__device__ __forceinline__ float bf2f(u16 u) {
  union { unsigned u; float f; } x; x.u = ((unsigned)u) << 16;
  return x.f;
}

__device__ __forceinline__ void gld_lds16(const void* g, void* l) {
  __builtin_amdgcn_global_load_lds(
      (const __attribute__((address_space(1))) void*)g,
      (__attribute__((address_space(3))) void*)l, 16, 0, 0);
}

// ---------------------------------------------------------------------------
struct CvtArgs { const float* src[8]; u16* dst[8]; int n4[8]; };

__global__ __launch_bounds__(256) void cvt_all(CvtArgs a, int total4, float* __restrict__ e) {
  int t = blockIdx.x * 256 + threadIdx.x;
  if (t >= total4) {
    int et = (t - total4) * 4;                  // emb flat base, < 1024*512
    if (et >= 1024 * 512) return;
#pragma unroll
    for (int u = 0; u < 4; ++u) {
      int idx = et + u;
      int c = idx & 511, sp = idx >> 9;
      int y = sp >> 5, xg = sp & 31;
      int j = c & 127, seg = c >> 7;
      float omega = expf(-(float)j * (9.210340371976184f / 128.f));
      float arg = (float)((seg < 2) ? y : xg) * omega;
      e[idx] = (seg & 1) ? cosf(arg) : sinf(arg);
    }
    return;
  }
#pragma unroll
  for (int s = 0; s < 8; ++s) {
    if (t < a.n4[s]) {
      const float* sp = a.src[s] + (long)t * 4;
      u16* dp = a.dst[s] + (long)t * 4;
      float4 v = *(const float4*)sp;
      dp[0] = f2bf(v.x); dp[1] = f2bf(v.y); dp[2] = f2bf(v.z); dp[3] = f2bf(v.w);
      return;
    }
    t -= a.n4[s];
  }
}

// ---------------------------------------------------------------------------
// S edge (permuted order: cls = index 1024): S[1024][kv] kv<=1024 and
// S[q][1024] q<1024 -> 2049 dots of length 512 per head. One dot per thread.
// Grid = nh*8 blocks, seg of 257 (8x257=2056>=2049).
// ---------------------------------------------------------------------------
__global__ __launch_bounds__(256) void s_edge(const u16* __restrict__ PQ,
                                              const u16* __restrict__ PK,
                                              u16* __restrict__ S, int nh) {
  int flat = blockIdx.x;                 // nh*8
  int head, seg;
  if (nh == 32) {
    int xcd = flat & 7, s = flat >> 3;   // s: 0..31
    head = xcd + 8 * (s >> 3);           // 0..31
    seg = s & 7;
  } else {
    head = flat >> 3;
    seg = flat & 7;
  }
  const u16* pq = PQ + (long)head * 1025 * 512;
  const u16* pk = PK + (long)head * 1025 * 512;
  u16* sh = S + (long)head * 1025 * 1088;
#pragma unroll
  for (int i = 0; i < 2; ++i) {
    int local = i * 256 + (int)threadIdx.x;
    if (local >= 257) continue;
    int e = seg * 257 + local;
    if (e >= 2049) continue;
    int q, kv;
    if (e < 1025) { q = 1024; kv = e; }
    else { q = e - 1025; kv = 1024; }
    const u16* a = pq + (long)q * 512;
    const u16* b = pk + (long)kv * 512;
    float acc = 0.f;
    for (int k8 = 0; k8 < 64; ++k8) {
      short8 av = *(const short8*)(a + k8 * 8);
      short8 bv = *(const short8*)(b + k8 * 8);
#pragma unroll
      for (int u = 0; u < 8; ++u) acc += bf2f((u16)av[u]) * bf2f((u16)bv[u]);
    }
    sh[(long)q * 1088 + kv] = f2bf(acc * 0.04419417382415922f);
  }
}

// ---------------------------------------------------------------------------
// Softmax: one WAVE per row, 4 rows/block. XCD head-grouped.
// ---------------------------------------------------------------------------
__global__ __launch_bounds__(256) void softmax_rows(u16* __restrict__ S) {
  int flat = blockIdx.x;
  int xcd = flat & 7, s0 = flat >> 3;
  int zi = s0 / 257, blk = s0 - zi * 257;
  int head = xcd + 8 * zi;
  int wv = threadIdx.x >> 6, lane = threadIdx.x & 63;
  int row_i = blk * 4 + wv;
  if (row_i > 1024) return;
  u16* row = S + ((long)head * 1025 + row_i) * 1088;
  float v[16];
  float mx = -1e30f;
#pragma unroll
  for (int i = 0; i < 4; ++i) {
    us4 p = *(const us4*)(row + i * 256 + lane * 4);
#pragma unroll
    for (int e = 0; e < 4; ++e) { v[i * 4 + e] = bf2f(p[e]); mx = fmaxf(mx, v[i * 4 + e]); }
  }
  float e1024 = (lane == 0) ? bf2f(row[1024]) : -1e30f;
  mx = fmaxf(mx, e1024);
  for (int o = 32; o > 0; o >>= 1) mx = fmaxf(mx, __shfl_xor(mx, o, 64));
  float s = 0.f;
#pragma unroll
  for (int i = 0; i < 16; ++i) { v[i] = __expf(v[i] - mx); s += v[i]; }
  e1024 = (lane == 0) ? __expf(e1024 - mx) : 0.f;
  s += e1024;
  for (int o = 32; o > 0; o >>= 1) s += __shfl_xor(s, o, 64);
  float inv = 1.0f / s;
#pragma unroll
  for (int i = 0; i < 4; ++i) {
    us4 q;
#pragma unroll
    for (int e = 0; e < 4; ++e) q[e] = f2bf(v[i * 4 + e] * inv);
    *(us4*)(row + i * 256 + lane * 4) = q;
  }
  if (lane < 16) {
    us4 q;
#pragma unroll
    for (int e = 0; e < 4; ++e) q[e] = 0;
    if (lane == 0) q[0] = f2bf(e1024 * inv);
    *(us4*)(row + 1024 + lane * 4) = q;
  }
}

// ---------------------------------------------------------------------------
__global__ __launch_bounds__(256) void reduce2(const float* __restrict__ part,
                                               const float* __restrict__ bd,
                                               float* __restrict__ out) {
  int t = blockIdx.x * 256 + threadIdx.x;    // < 524800
  long i = (long)t * 4;
  const long STR = 4100ll * 512;
  float4 a = *(const float4*)(part + i);
  float4 b = *(const float4*)(part + i + STR);
  float4 bb = *(const float4*)(bd + (int)(i & 511));
  float4 r;
  r.x = a.x + b.x + bb.x;
  r.y = a.y + b.y + bb.y;
  r.z = a.z + b.z + bb.z;
  r.w = a.w + b.w + bb.w;
  *(float4*)(out + i) = r;
}

// ---------------------------------------------------------------------------
// GEMM-BT: C[m][n] = sum_k A[m][k]*B[n][k], bf16, 128x128 tile, BK=64,
// staging XOR swizzle. Token order: cls at 1024 in PQ/PK/S/PVt.
// Modes:
//  0 PROJ : A=xb, B=[Wq|Wk|Wv] -> Q/K/V (+bias via acc init); cls rows also
//           written to PQ/PK row 1024 and PVt col 1024 (p0/p1/p2).
//  1 POOL : 1D XCD; bz=0: Q*Wpq (+emb) -> PQ rows 0..1023; bz=1: K*Wpk -> PK
//  2 POOLT: 1D XCD; V*Wpv -> PVt[ch][sp] via LDS-transposed vector epilogue
//  3 S    : 1D XCD head-grouped; interior 8x8 tiles only
//  4 O    : 1D XCD head-grouped; S*PVt^T -> stacked (+Q resid), l=perm(q)
//  5 FIN  : A=stk, B=Wd, split-K x2 -> f32 partials
// ---------------------------------------------------------------------------
struct GP {
  const u16* A; const u16* A2; const u16* B; const u16* B2;
  const float* c0; const float* c1; const float* c2;
  const float* emb; const u16* resid;
  u16* o0; u16* o1; u16* o2;
  u16* p0; u16* p1; u16* p2;
  float* of; int bz0;
};

template <int MODE>
__global__ __launch_bounds__(256) void gemm_bt(GP g) {
  constexpr int KLEN = (MODE == 5) ? 2048 : ((MODE == 4) ? 1088 : 512);
  constexpr int KITER = KLEN / 64;
  constexpr bool LDSEP = (MODE == 0 || MODE == 1 || MODE == 3 || MODE == 4);
  __shared__ u16 smem[16384];          // As | Bs staging; epilogue tile reuse
  u16* As = smem;
  u16* Bs = smem + 8192;
  const int tid = threadIdx.x;
  const int lane = tid & 63;
  const int wv = tid >> 6;
  const int wr = wv >> 1, wc = wv & 1;
  const int ccol = lane & 15;
  const int rgrp = lane >> 4;

  // Block -> (mt, nt, bz). XCD grouping (flat&7) for modes 1/2/3/4.
  int mt, nt, bz;
  if constexpr (MODE == 3 || MODE == 4) {
    constexpr int PER = (MODE == 3) ? 64 : 36;   // mode3: interior 8x8 only
    constexpr int NTW = (MODE == 3) ? 8 : 4;
    int flat = blockIdx.x;
    int xcd = flat & 7, s = flat >> 3;
    bz = xcd + 8 * (s / PER);
    int tile = s % PER;
    mt = tile / NTW;
    nt = tile % NTW;
  } else if constexpr (MODE == 1) {
    int flat = blockIdx.x;               // 2048 blocks
    int xcd = flat & 7, s = flat >> 3;   // s: 0..255
    bz = s >> 7;                         // 0 = Q-pool, 1 = K-pool
    int rem = s & 127;
    mt = xcd * 32 + (rem >> 2);          // contiguous 32-mt slice per XCD
    nt = rem & 3;
  } else if constexpr (MODE == 2) {
    int flat = blockIdx.x;               // 1024 blocks
    int xcd = flat & 7, s = flat >> 3;   // s: 0..127
    bz = 0;
    mt = xcd * 32 + (s >> 2);
    nt = s & 3;
  } else {
    mt = blockIdx.y; nt = blockIdx.x; bz = blockIdx.z;
  }
  const int gbz = g.bz0 + bz;

  const u16* Ap = g.A;
  const u16* Bp = g.B;
  if constexpr (MODE == 1) {
    if (bz == 1) { Ap = g.A2; Bp = g.B2; }
  }

  int a_row[4], b_row[4], kx[4];
#pragma unroll
  for (int c = 0; c < 4; ++c) {
    int idx = c * 256 + tid;
    int row = idx >> 3;                       // 0..127
    kx[c] = ((idx & 7) ^ (row & 7)) * 8;      // swizzled k-chunk offset (elems)
    {
      int r = mt * 128 + row;
      int off;
      if constexpr (MODE == 0) { r = r < 4099 ? r : 4099; off = r * 512; }
      else if constexpr (MODE == 1 || MODE == 2) { off = ((r >> 10) * 1025 + 1 + (r & 1023)) * 512; }
      else if constexpr (MODE == 3) { off = gbz * (1025 * 512) + r * 512; }
      else if constexpr (MODE == 4) { r = r < 1024 ? r : 1024; off = bz * (1025 * 1088) + r * 1088; }
      else { r = r < 4099 ? r : 4099; off = r * 4096; }
      a_row[c] = off;
    }
    {
      int r = nt * 128 + row;
      int off;
      if constexpr (MODE == 3) { off = gbz * (1025 * 512) + r * 512; }
      else if constexpr (MODE == 4) { off = gbz * (512 * 1088) + r * 1088; }
      else if constexpr (MODE == 5) { off = r * 4096; }
      else { off = r * 512; }
      b_row[c] = off;
    }
  }

  // Accumulators: modes 0/1/2 initialize with the per-column bias.
  floatx4 acc[4][4];
  {
    float binit[4] = {0.f, 0.f, 0.f, 0.f};
    if constexpr (MODE == 0) {
      int sec = nt >> 5;
      const float* bs = (sec == 0) ? g.c0 : (sec == 1) ? g.c1 : g.c2;
#pragma unroll
      for (int j = 0; j < 4; ++j) binit[j] = bs[(nt & 31) * 128 + wc * 64 + j * 16 + ccol];
    }
    if constexpr (MODE == 1) {
      const float* bs = bz ? g.c1 : g.c0;
#pragma unroll
      for (int j = 0; j < 4; ++j) binit[j] = bs[nt * 128 + wc * 64 + j * 16 + ccol];
    }
    if constexpr (MODE == 2) {
#pragma unroll
      for (int j = 0; j < 4; ++j) binit[j] = g.c0[nt * 128 + wc * 64 + j * 16 + ccol];
    }
#pragma unroll
    for (int i = 0; i < 4; ++i)
#pragma unroll
      for (int j = 0; j < 4; ++j)
#pragma unroll
        for (int rr = 0; rr < 4; ++rr) acc[i][j][rr] = binit[j];
  }

  const int kbase = (MODE == 5) ? bz * 2048 : 0;
  const int l15 = lane & 15;
  const int lq = lane >> 4;
  const int l7 = lane & 7;

  for (int kt = 0; kt < KITER; ++kt) {
    const int k0 = kbase + kt * 64;
#pragma unroll
    for (int c = 0; c < 4; ++c)
      gld_lds16(Ap + a_row[c] + k0 + kx[c], (char*)As + (c * 256 + wv * 64) * 16);
#pragma unroll
    for (int c = 0; c < 4; ++c)
      gld_lds16(Bp + b_row[c] + k0 + kx[c], (char*)Bs + (c * 256 + wv * 64) * 16);
    __syncthreads();
#pragma unroll
    for (int ks = 0; ks < 2; ++ks) {
      const int ch = ((ks * 4 + lq) ^ l7) * 8;
      short8 af[4], bf[4];
#pragma unroll
      for (int i = 0; i < 4; ++i)
        af[i] = *(const short8*)(As + (wr * 64 + i * 16 + l15) * 64 + ch);
#pragma unroll
      for (int j = 0; j < 4; ++j)
        bf[j] = *(const short8*)(Bs + (wc * 64 + j * 16 + l15) * 64 + ch);
#pragma unroll
      for (int i = 0; i < 4; ++i)
#pragma unroll
        for (int j = 0; j < 4; ++j)
          acc[i][j] = __builtin_amdgcn_mfma_f32_16x16x32_bf16(af[i], bf[j], acc[i][j], 0, 0, 0);
    }
    __syncthreads();
  }

  // ---- Epilogue ---- (C/D frag: col = lane&15, row = (lane>>4)*4 + reg)
  if constexpr (LDSEP) {
#pragma unroll
    for (int i = 0; i < 4; ++i)
#pragma unroll
      for (int j = 0; j < 4; ++j)
#pragma unroll
        for (int rr = 0; rr < 4; ++rr) {
          int lr = wr * 64 + i * 16 + rgrp * 4 + rr;
          int lc = wc * 64 + j * 16 + ccol;
          float v = acc[i][j][rr];
          if constexpr (MODE == 3) v *= 0.04419417382415922f;
          smem[lr * 128 + (lc ^ (rgrp << 4))] = f2bf(v);
        }
    __syncthreads();
#pragma unroll
    for (int q = 0; q < 8; ++q) {
      int cid = q * 256 + tid;
      int r = cid >> 4;                 // 0..127
      int c = cid & 15;                 // chunk
      int pc = c ^ ((((unsigned)r >> 2) & 3) << 1);
      short8 val = *(const short8*)(smem + r * 128 + pc * 8);
      int grow = mt * 128 + r;
      if constexpr (MODE == 0) {
        if (grow < 4100) {
          int sec = nt >> 5;                     // block-uniform
          int col = (nt & 31) * 128 + c * 8;     // 0..4095
          u16* ob = (sec == 0) ? g.o0 : (sec == 1) ? g.o1 : g.o2;
          int b = grow / 1025, l = grow - b * 1025;
          int n = col >> 9, ch2 = col & 511;
          long bn = (long)b * 8 + n;
          *(short8*)(ob + (bn * 1025 + l) * 512 + ch2) = val;
          if (l == 0) {                          // cls fold -> permuted idx 1024
            if (sec == 0) *(short8*)(g.p0 + (bn * 1025 + 1024) * 512 + ch2) = val;
            else if (sec == 1) *(short8*)(g.p1 + (bn * 1025 + 1024) * 512 + ch2) = val;
            else {
#pragma unroll
              for (int e = 0; e < 8; ++e)
                g.p2[(bn * 512 + ch2 + e) * 1088 + 1024] = (u16)val[e];
            }
          }
        }
      } else if constexpr (MODE == 1) {
        int bn = grow >> 10, sp = grow & 1023;
        int gcol = nt * 128 + c * 8;             // 0..511
        short8 outv = val;
        if (bz == 0) {
          const float* ep = g.emb + sp * 512 + gcol;
          float4 e0 = *(const float4*)ep;
          float4 e1 = *(const float4*)(ep + 4);
          float ee[8] = {e0.x, e0.y, e0.z, e0.w, e1.x, e1.y, e1.z, e1.w};
#pragma unroll
          for (int e = 0; e < 8; ++e) outv[e] = (short)f2bf(bf2f((u16)val[e]) + ee[e]);
        }
        u16* dst = (bz == 0) ? g.o0 : g.o1;
        *(short8*)(dst + ((long)bn * 1025 + sp) * 512 + gcol) = outv;   // permuted
      } else if constexpr (MODE == 3) {
        // interior only: grow < 1024, gcol < 1024 guaranteed
        *(short8*)(g.o0 + ((long)bz * 1025 + grow) * 1088 + nt * 128 + c * 8) = val;
      } else {  // MODE 4
        if (grow <= 1024) {
          int gcol0 = nt * 128 + c * 8;          // 0..511
          short8 outv = val;
          int l = (grow == 1024) ? 0 : grow + 1; // permuted q -> original l
          if (grow < 1024) {                     // spatial: add Q residual
            short8 rs = *(const short8*)(g.resid + ((long)gbz * 1025 + l) * 512 + gcol0);
#pragma unroll
            for (int e = 0; e < 8; ++e)
              outv[e] = (short)f2bf(bf2f((u16)val[e]) + bf2f((u16)rs[e]));
          }
          int b = gbz >> 3, n = gbz & 7;
          *(short8*)(g.o0 + (((long)b * 1025 + l) * 8 + n) * 512 + gcol0) = outv;
        }
      }
    }
  } else if constexpr (MODE == 2) {
    // LDS-transposed epilogue: deposit [ch_local][sp_local], vector store
    // along sp (aligned -- spatial starts at offset 0 in permuted PVt).
#pragma unroll
    for (int i = 0; i < 4; ++i)
#pragma unroll
      for (int j = 0; j < 4; ++j)
#pragma unroll
        for (int rr = 0; rr < 4; ++rr) {
          int lr2 = wc * 64 + j * 16 + ccol;            // ch-local
          int lc2 = wr * 64 + i * 16 + rgrp * 4 + rr;   // sp-local
          smem[lr2 * 128 + (lc2 ^ ((lr2 & 15) << 3))] = f2bf(acc[i][j][rr]);
        }
    __syncthreads();
    {
      int bn = mt >> 3, sp0 = (mt & 7) * 128;
#pragma unroll
      for (int q = 0; q < 8; ++q) {
        int cid = q * 256 + tid;
        int r = cid >> 4;                 // ch-local 0..127
        int c = cid & 15;                 // sp chunk
        int pc = c ^ (r & 15);
        short8 val = *(const short8*)(smem + r * 128 + pc * 8);
        int ch = nt * 128 + r;
        *(short8*)(g.o0 + ((long)(bn * 512 + ch)) * 1088 + sp0 + c * 8) = val;
      }
    }
  } else {
    // Scalar epilogue for mode 5 (f32 partials).
#pragma unroll
    for (int i = 0; i < 4; ++i) {
#pragma unroll
      for (int j = 0; j < 4; ++j) {
        const int gcol = nt * 128 + wc * 64 + j * 16 + ccol;
#pragma unroll
        for (int rr = 0; rr < 4; ++rr) {
          const int grow = mt * 128 + wr * 64 + i * 16 + rgrp * 4 + rr;
          if (grow < 4100)
            g.of[((long)bz * 4100 + grow) * 512 + gcol] = acc[i][j][rr];
        }
      }
    }
  }
}

// ---------------------------------------------------------------------------
extern "C" void kernel_launch(void* const* d_in, const int* in_sizes, int n_in,
                              void* d_out, int out_size, void* d_ws, size_t ws_size,
                              hipStream_t stream) {
  const float* x   = (const float*)d_in[0];
  const float* Wq  = (const float*)d_in[1];
  const float* bq  = (const float*)d_in[2];
  const float* Wk  = (const float*)d_in[3];
  const float* bk  = (const float*)d_in[4];
  const float* Wv  = (const float*)d_in[5];
  const float* bv  = (const float*)d_in[6];
  const float* Wpq = (const float*)d_in[7];
  const float* bpq = (const float*)d_in[8];
  const float* Wpk = (const float*)d_in[9];
  const float* bpk = (const float*)d_in[10];
  const float* Wpv = (const float*)d_in[11];
  const float* bpv = (const float*)d_in[12];
  const float* Wd  = (const float*)d_in[13];
  const float* bd  = (const float*)d_in[14];
  float* out = (float*)d_out;

  char* ws = (char*)d_ws;
  size_t off = 0;
  auto alloc = [&](size_t bytes) {
    char* p = ws + off;
    off += (bytes + 255) & ~(size_t)255;
    return p;
  };
  // Persistent through attention:
  u16* Wpqb = (u16*)alloc(512ull * 512 * 2);
  u16* Wpkb = (u16*)alloc(512ull * 512 * 2);
  u16* Wpvb = (u16*)alloc(512ull * 512 * 2);
  u16* Wdb  = (u16*)alloc(4096ull * 512 * 2);
  u16* Q    = (u16*)alloc(32ull * 1025 * 512 * 2);
  u16* PQ   = (u16*)alloc(32ull * 1025 * 512 * 2);   // later: f32 partials
  u16* PK   = (u16*)alloc(32ull * 1025 * 512 * 2);   // later: stk (nchunk=1)
  u16* PVt  = (u16*)alloc(32ull * 512 * 1088 * 2);
  // Dead-by-attention group (S aliases from here):
  size_t s_off = off;
  u16* K    = (u16*)alloc(32ull * 1025 * 512 * 2);
  u16* V    = (u16*)alloc(32ull * 1025 * 512 * 2);
  u16* xb   = (u16*)alloc(4100ull * 512 * 2);
  u16* Wqb  = (u16*)alloc(4096ull * 512 * 2);   // Wqb|Wkb|Wvb contiguous
  u16* Wkb  = (u16*)alloc(4096ull * 512 * 2);
  u16* Wvb  = (u16*)alloc(4096ull * 512 * 2);
  float* embp = (float*)alloc(1024ull * 512 * 4);
  size_t fixed_need = off;
  u16* S = (u16*)(ws + s_off);
  float* part = (float*)PQ;   // PQ dead before partials written
  (void)in_sizes; (void)n_in; (void)out_size;

  const size_t sbytes = 1025ull * 1088 * 2;
  size_t need1 = s_off + 32ull * sbytes;
  size_t need2 = s_off + 16ull * sbytes;
  size_t stk4_off = s_off + ((8ull * sbytes + 255) & ~(size_t)255);
  size_t need4 = stk4_off + 4100ull * 4096 * 2;
  int nchunk;
  u16* stk;
  if (ws_size >= need1)      { nchunk = 1; stk = PK; }   // PK dead after mode 3
  else if (ws_size >= need2 && ws_size >= fixed_need) { nchunk = 2; stk = PK; }
  else if (ws_size >= need4 && ws_size >= fixed_need) {
    nchunk = 4; stk = (u16*)(ws + stk4_off);
  } else return;  // clean fail instead of GPU fault
  if (nchunk == 2) {
    size_t stk2_off = s_off + ((16ull * sbytes + 255) & ~(size_t)255);
    if (ws_size >= stk2_off + 4100ull * 4096 * 2) stk = (u16*)(ws + stk2_off);
    else {
      nchunk = 4;
      if (ws_size >= need4) stk = (u16*)(ws + stk4_off);
      else return;
    }
  }
  int hpc = 32 / nchunk;

  // 1) dtype conversions + pos-embed (one launch)
  CvtArgs ca;
  ca.src[0] = x;   ca.dst[0] = xb;   ca.n4[0] = 4100 * 512 / 4;
  ca.src[1] = Wq;  ca.dst[1] = Wqb;  ca.n4[1] = 4096 * 512 / 4;
  ca.src[2] = Wk;  ca.dst[2] = Wkb;  ca.n4[2] = 4096 * 512 / 4;
  ca.src[3] = Wv;  ca.dst[3] = Wvb;  ca.n4[3] = 4096 * 512 / 4;
  ca.src[4] = Wpq; ca.dst[4] = Wpqb; ca.n4[4] = 512 * 512 / 4;
  ca.src[5] = Wpk; ca.dst[5] = Wpkb; ca.n4[5] = 512 * 512 / 4;
  ca.src[6] = Wpv; ca.dst[6] = Wpvb; ca.n4[6] = 512 * 512 / 4;
  ca.src[7] = Wd;  ca.dst[7] = Wdb;  ca.n4[7] = 512 * 4096 / 4;
  int total4 = 0;
  for (int s = 0; s < 8; ++s) total4 += ca.n4[s];
  int grid1 = (total4 + 1024 * 512 / 4 + 255) / 256;
  cvt_all<<<grid1, 256, 0, stream>>>(ca, total4, embp);

  // 2) merged Q+K+V projection; cls rows folded into PQ/PK/PVt (idx 1024)
  {
    GP g = {};
    g.A = xb; g.B = Wqb;
    g.c0 = bq; g.c1 = bk; g.c2 = bv;
    g.o0 = Q; g.o1 = K; g.o2 = V;
    g.p0 = PQ; g.p1 = PK; g.p2 = PVt;
    gemm_bt<0><<<dim3(96, 33, 1), 256, 0, stream>>>(g);
  }

  // 3) pools: Q(+emb) and K in one mode-1 dispatch; V pool (LDS-T epilogue)
  {
    GP g = {};
    g.A = Q; g.A2 = K; g.B = Wpqb; g.B2 = Wpkb;
    g.c0 = bpq; g.c1 = bpk; g.emb = embp;
    g.o0 = PQ; g.o1 = PK;
    gemm_bt<1><<<dim3(2048, 1, 1), 256, 0, stream>>>(g);
  }
  {
    GP g = {};
    g.A = V; g.B = Wpvb; g.c0 = bpv; g.o0 = PVt;
    gemm_bt<2><<<dim3(1024, 1, 1), 256, 0, stream>>>(g);
  }
  // K, V, xb, Wqkv, embp now dead -> S aliases them.

  // 4) attention: interior S tiles + S edge -> softmax -> O (+Q resid).
  for (int c = 0; c < nchunk; ++c) {
    GP g3 = {}; g3.A = PQ; g3.B = PK; g3.o0 = S; g3.bz0 = c * hpc;
    gemm_bt<3><<<dim3(64 * hpc, 1, 1), 256, 0, stream>>>(g3);
    s_edge<<<hpc * 8, 256, 0, stream>>>(
        PQ + (long)c * hpc * 1025 * 512, PK + (long)c * hpc * 1025 * 512, S, hpc);
    softmax_rows<<<257 * hpc, 256, 0, stream>>>(S);
    GP g4 = {}; g4.A = S; g4.B = PVt; g4.resid = Q; g4.o0 = stk; g4.bz0 = c * hpc;
    gemm_bt<4><<<dim3(36 * hpc, 1, 1), 256, 0, stream>>>(g4);
  }
  // PQ dead -> f32 partials alias it.

  // 5) final projection, split-K x2 -> partials, then reduce (+bias)
  {
    GP g = {}; g.A = stk; g.B = Wdb; g.of = part;
    gemm_bt<5><<<dim3(4, 33, 2), 256, 0, stream>>>(g);
  }
  reduce2<<<(4100 * 512 / 4 + 255) / 256, 256, 0, stream>>>(part, bd, out);
}